// Round 18
// baseline (68.217 us; speedup 1.0000x reference)
//
#include <hip/hip_runtime.h>

#define TEMP 10.0f
#define NS 4096
#define BB 512
#define DDIM 512
#define NCLS 10
#define LDSP 72

typedef short bf16x8 __attribute__((ext_vector_type(8)));
typedef float f32x4 __attribute__((ext_vector_type(4)));

__device__ inline short f2bf(float f) {
    unsigned u = __builtin_bit_cast(unsigned, f);
    u += 0x7FFFu + ((u >> 16) & 1u);      // round-to-nearest-even
    return (short)(u >> 16);
}
__device__ inline float bf2f(short h) {
    unsigned u = ((unsigned)(unsigned short)h) << 16;
    return __builtin_bit_cast(float, u);
}

// =============== block-wide sum helper (256 threads) ===============
__device__ inline float block_sum(float s, float* red) {
    #pragma unroll
    for (int off = 32; off > 0; off >>= 1) s += __shfl_down(s, off);
    int wid = threadIdx.x >> 6;
    if ((threadIdx.x & 63) == 0) red[wid] = s;
    __syncthreads();
    float tot = red[0] + red[1] + red[2] + red[3];
    __syncthreads();
    return tot;
}

// =============== prep ===============
// blocks [0,1024)    : star rows -> Sb bf16 + sn2 + scol + spart[bid]
// blocks [1024,1152) : x rows    -> Xb bf16 + xn2 + xcol (+ midx init on block 1024)
// blocks [1152,1664) : from 64x64 tiles -> Fb + FTb + rowpart (fp32 row-sq) + fpart2 (colsum)
__global__ __launch_bounds__(256)
void prep(const float* __restrict__ x, const float* __restrict__ star,
          const float* __restrict__ from,
          short* __restrict__ Xb, short* __restrict__ Sb,
          short* __restrict__ FTb, short* __restrict__ Fb,
          float* __restrict__ xn2, float* __restrict__ sn2,
          float* __restrict__ scol, float* __restrict__ xcol, int* __restrict__ midx,
          float* __restrict__ spart, float* __restrict__ fpart2,
          float* __restrict__ rowpart)
{
    __shared__ short tile[64][LDSP];      // conv path aliases as float cp[2048]
    __shared__ float cpart[16][65];
    int bid = blockIdx.x, t = threadIdx.x;
    if (bid < 1152) {
        const float* in; short* outb; float* n2; float* colb; float* part; int rowbase;
        if (bid < 1024)      { in = star; outb = Sb; n2 = sn2; colb = scol; rowbase = bid * 4;
                               part = spart + (size_t)bid * 512; }
        else                 { in = x;    outb = Xb; n2 = xn2; colb = xcol; rowbase = (bid - 1024) * 4;
                               part = nullptr; }
        if (bid == 1024) { midx[t] = NS; midx[256 + t] = NS; }
        int w = t >> 6;
        int row = rowbase + w;
        int l = t & 63;
        const float4* p = (const float4*)(in + (size_t)row * DDIM) + l * 2;
        float4 a = p[0], b = p[1];
        float s = a.x*a.x + a.y*a.y + a.z*a.z + a.w*a.w
                + b.x*b.x + b.y*b.y + b.z*b.z + b.w*b.w;
        bf16x8 h;
        h[0]=f2bf(a.x); h[1]=f2bf(a.y); h[2]=f2bf(a.z); h[3]=f2bf(a.w);
        h[4]=f2bf(b.x); h[5]=f2bf(b.y); h[6]=f2bf(b.z); h[7]=f2bf(b.w);
        *(bf16x8*)(outb + (size_t)row * DDIM + l * 8) = h;
        #pragma unroll
        for (int off = 32; off > 0; off >>= 1) s += __shfl_down(s, off);
        if (l == 0) {
            n2[row] = s;
            if (colb) colb[row] = a.x;
        }
        if (part) {
            float* cp = (float*)tile;    // [4][512]
            *(float4*)&cp[w * 512 + l * 8]     = a;
            *(float4*)&cp[w * 512 + l * 8 + 4] = b;
            __syncthreads();
            int c = t * 2;
            float2 o;
            o.x = cp[c]     + cp[512 + c]     + cp[1024 + c]     + cp[1536 + c];
            o.y = cp[c + 1] + cp[512 + c + 1] + cp[1024 + c + 1] + cp[1536 + c + 1];
            *(float2*)&part[c] = o;
        }
        return;
    }
    // ---- from 64x64 tile: convert + transpose + fp32 partials (single HBM pass) ----
    int tid2 = bid - 1152;
    int n0 = (tid2 & 63) * 64, d0 = (tid2 >> 6) * 64;
    int r = t >> 4, c4 = (t & 15) * 4;
    float4 colacc = {0.f, 0.f, 0.f, 0.f};
    float rowacc[4];
    #pragma unroll
    for (int q = 0; q < 4; ++q) {
        int rr = q * 16;
        float4 v = *(const float4*)(from + (size_t)(n0 + r + rr) * DDIM + d0 + c4);
        tile[r + rr][c4 + 0] = f2bf(v.x);
        tile[r + rr][c4 + 1] = f2bf(v.y);
        tile[r + rr][c4 + 2] = f2bf(v.z);
        tile[r + rr][c4 + 3] = f2bf(v.w);
        rowacc[q] = v.x*v.x + v.y*v.y + v.z*v.z + v.w*v.w;
        colacc.x += v.x; colacc.y += v.y; colacc.z += v.z; colacc.w += v.w;
    }
    // row-square partials: reduce over the 16 lanes owning each row (fp32-exact path)
    #pragma unroll
    for (int q = 0; q < 4; ++q) {
        float s = rowacc[q];
        #pragma unroll
        for (int off = 8; off > 0; off >>= 1) s += __shfl_down(s, off, 16);
        if ((t & 15) == 0)
            rowpart[(size_t)(d0 >> 6) * NS + n0 + r + q * 16] = s;
    }
    *(float4*)&cpart[r][c4] = colacc;
    __syncthreads();
    // colsum partials
    if (t < 64) {
        float s = 0.f;
        #pragma unroll
        for (int q = 0; q < 16; ++q) s += cpart[q][t];
        fpart2[(size_t)(n0 >> 6) * 512 + d0 + t] = s;
    }
    // Fb rows from tile
    {
        int tr = t >> 2, tc = (t & 3) * 16;
        short* fo = Fb + (size_t)(n0 + tr) * DDIM + d0 + tc;
        *(bf16x8*)fo       = *(bf16x8*)&tile[tr][tc];
        *(bf16x8*)(fo + 8) = *(bf16x8*)&tile[tr][tc + 8];
    }
    // FTb transpose
    {
        int dr = t >> 2, nco = (t & 3) * 16;
        short tmp[16];
        #pragma unroll
        for (int q = 0; q < 16; ++q) tmp[q] = tile[nco + q][dr];
        short* op = FTb + (size_t)(d0 + dr) * NS + n0 + nco;
        *(bf16x8*)op       = *(bf16x8*)tmp;
        *(bf16x8*)(op + 8) = *(bf16x8*)(tmp + 8);
    }
}

// ===== finmatch: 66 blocks =====
// 0..15 : star colsum reduce (1024 partials) -> sbar
// 16..31: from colsum reduce (64 partials)   -> fbar
// 32    : sms from sn2
// 33    : fms from rowpart (sum of all row-sq partials)
// 34..49: exact-match scan -> midx
// 50..65: fn2[n] = sum_dt rowpart[dt][n]
__global__ __launch_bounds__(256)
void finmatch(const float* __restrict__ spart, const float* __restrict__ fpart2,
              const float* __restrict__ rowpart,
              const float* __restrict__ sn2, float* __restrict__ fn2,
              float* __restrict__ sbar, float* __restrict__ fbar,
              float* __restrict__ sms, float* __restrict__ fms,
              const float* __restrict__ x, const float* __restrict__ star,
              const float* __restrict__ scol, const float* __restrict__ xcol,
              int* __restrict__ midx)
{
    int bid = blockIdx.x, t = threadIdx.x;
    if (bid < 16) {
        __shared__ float red2[8][33];
        int c0 = bid * 32;
        int c = c0 + (t & 31);
        int p0 = (t >> 5) * 128;
        float s = 0.f;
        #pragma unroll 8
        for (int p = 0; p < 128; ++p)
            s += spart[(size_t)(p0 + p) * 512 + c];
        red2[t >> 5][t & 31] = s;
        __syncthreads();
        if (t < 32) {
            float tot = 0.f;
            #pragma unroll
            for (int q = 0; q < 8; ++q) tot += red2[q][t];
            sbar[c0 + t] = tot * (1.0f / NS);
        }
        return;
    }
    if (bid < 32) {
        __shared__ float red2[8][33];
        int c0 = (bid - 16) * 32;
        int c = c0 + (t & 31);
        int p0 = (t >> 5) * 8;
        float s = 0.f;
        #pragma unroll
        for (int p = 0; p < 8; ++p)
            s += fpart2[(size_t)(p0 + p) * 512 + c];
        red2[t >> 5][t & 31] = s;
        __syncthreads();
        if (t < 32) {
            float tot = 0.f;
            #pragma unroll
            for (int q = 0; q < 8; ++q) tot += red2[q][t];
            fbar[c0 + t] = tot * (1.0f / NS);
        }
        return;
    }
    if (bid == 32) {
        __shared__ float red[4];
        float s = 0.f;
        #pragma unroll
        for (int q = 0; q < 16; ++q) s += sn2[q * 256 + t];
        float tot = block_sum(s, red);
        if (t == 0) sms[0] = tot * (1.0f / NS);
        return;
    }
    if (bid == 33) {
        __shared__ float red[4];
        float s = 0.f;
        #pragma unroll 8
        for (int q = 0; q < 128; ++q) s += rowpart[(size_t)q * 256 + t];
        float tot = block_sum(s, red);
        if (t == 0) fms[0] = tot * (1.0f / NS);
        return;
    }
    if (bid < 50) {
        // ---- exact-match scan ----
        __shared__ float xl[BB];
        *(float2*)&xl[t * 2] = *(const float2*)&xcol[t * 2];
        __syncthreads();
        int n = (bid - 34) * 256 + t;
        float sv = scol[n];
        #pragma unroll 4
        for (int b4 = 0; b4 < BB; b4 += 4) {
            float4 xv = *(const float4*)&xl[b4];
            if (xv.x == sv || xv.y == sv || xv.z == sv || xv.w == sv) {
                #pragma unroll
                for (int j = 0; j < 4; ++j) {
                    int b = b4 + j;
                    if (xl[b] == sv) {
                        const float* xr = x + (size_t)b * DDIM;
                        const float* sr = star + (size_t)n * DDIM;
                        bool eq = true;
                        for (int k = 0; k < DDIM && eq; k += 4) {
                            float4 a = *(const float4*)(xr + k);
                            float4 c4v = *(const float4*)(sr + k);
                            eq = (a.x == c4v.x) && (a.y == c4v.y) &&
                                 (a.z == c4v.z) && (a.w == c4v.w);
                        }
                        if (eq) atomicMin(&midx[b], n);
                    }
                }
            }
        }
        return;
    }
    // ---- fn2 assembly ----
    int n = (bid - 50) * 256 + t;
    float s = 0.f;
    #pragma unroll
    for (int dt = 0; dt < 8; ++dt) s += rowpart[(size_t)dt * NS + n];
    fn2[n] = s;
}

// ===== esc1k: 128 blocks, escale1[b] = -T / (sms + xn2[b] - 2*sbar.x_b) =====
__global__ __launch_bounds__(256)
void esc1k(const float* __restrict__ x, const float* __restrict__ sbar,
           const float* __restrict__ sms, const float* __restrict__ xn2,
           float* __restrict__ escale1)
{
    int t = threadIdx.x;
    int lane = t & 63, w = t >> 6;
    int b = blockIdx.x * 4 + w;
    const float4* xp = (const float4*)(x + (size_t)b * DDIM) + lane * 2;
    const float4* sp = (const float4*)sbar + lane * 2;
    float4 xa = xp[0], xb = xp[1], sa = sp[0], sb = sp[1];
    float dot = xa.x*sa.x + xa.y*sa.y + xa.z*sa.z + xa.w*sa.w
              + xb.x*sb.x + xb.y*sb.y + xb.z*sb.z + xb.w*sb.w;
    #pragma unroll
    for (int m = 32; m > 0; m >>= 1) dot += __shfl_xor(dot, m);
    if (lane == 0)
        escale1[b] = -TEMP / (sms[0] + xn2[b] - 2.0f * dot);
}

// ====== MFMA GEMM + fused sqdist/exp epilogue ======
// MODE 1: Eout bf16 write + sumEp[m][64]. MODE 2: label bins -> ybin[nt][b][NCLS].
template<int MODE>
__global__ __launch_bounds__(256)
void gemm_exp(const short* __restrict__ A, const short* __restrict__ B,
              const float* __restrict__ an2, const float* __restrict__ bn2,
              const float* __restrict__ escale, short* __restrict__ Eout,
              float* __restrict__ sumEp, const int* __restrict__ labels,
              float* __restrict__ ybin, int nt)
{
    __shared__ short As[2][64][LDSP];
    __shared__ short Bs[2][64][LDSP];
    __shared__ float se[2][64];
    __shared__ float esum[64][65];
    __shared__ float ybq[64][4][NCLS];
    __shared__ int lbl_l[64];
    const int K = DDIM;
    int t = threadIdx.x;
    int m0 = blockIdx.x * 64;
    int n0 = blockIdx.y * 64;
    int wid = t >> 6, lane = t & 63;
    int wr = wid >> 1, wc = wid & 1;
    int lr = lane & 15, lk = lane >> 4;

    int ar = t >> 2, ak = (t & 3) * 16;
    const short* Ag = A + (size_t)(m0 + ar) * K + ak;
    const short* Bg = B + (size_t)(n0 + ar) * K + ak;

    f32x4 acc[2][2] = {};
    bf16x8 ra0 = *(const bf16x8*)Ag;
    bf16x8 ra1 = *(const bf16x8*)(Ag + 8);
    bf16x8 rb0 = *(const bf16x8*)Bg;
    bf16x8 rb1 = *(const bf16x8*)(Bg + 8);
    int cur = 0;
    *(bf16x8*)&As[0][ar][ak]     = ra0;
    *(bf16x8*)&As[0][ar][ak + 8] = ra1;
    *(bf16x8*)&Bs[0][ar][ak]     = rb0;
    *(bf16x8*)&Bs[0][ar][ak + 8] = rb1;
    if (MODE == 2 && t < 64) lbl_l[t] = labels[n0 + t];

    for (int it = 0; it < nt; ++it) {
        __syncthreads();
        if (it + 1 < nt) {
            int ko = (it + 1) * 64;
            ra0 = *(const bf16x8*)(Ag + ko);
            ra1 = *(const bf16x8*)(Ag + ko + 8);
            rb0 = *(const bf16x8*)(Bg + ko);
            rb1 = *(const bf16x8*)(Bg + ko + 8);
        }
        #pragma unroll
        for (int ks = 0; ks < 2; ++ks) {
            int k0 = ks * 32 + lk * 8;
            bf16x8 af[2], bfr[2];
            #pragma unroll
            for (int i = 0; i < 2; ++i)
                af[i] = *(const bf16x8*)&As[cur][wr * 32 + i * 16 + lr][k0];
            #pragma unroll
            for (int j = 0; j < 2; ++j)
                bfr[j] = *(const bf16x8*)&Bs[cur][wc * 32 + j * 16 + lr][k0];
            #pragma unroll
            for (int i = 0; i < 2; ++i)
                #pragma unroll
                for (int j = 0; j < 2; ++j)
                    acc[i][j] = __builtin_amdgcn_mfma_f32_16x16x32_bf16(
                        af[i], bfr[j], acc[i][j], 0, 0, 0);
        }
        if (it + 1 < nt) {
            cur ^= 1;
            *(bf16x8*)&As[cur][ar][ak]     = ra0;
            *(bf16x8*)&As[cur][ar][ak + 8] = ra1;
            *(bf16x8*)&Bs[cur][ar][ak]     = rb0;
            *(bf16x8*)&Bs[cur][ar][ak + 8] = rb1;
        }
    }
    // ---- epilogue ----
    float bn2v[2];
    int gnv[2];
    #pragma unroll
    for (int j = 0; j < 2; ++j) { gnv[j] = n0 + wc * 32 + j * 16 + lr; bn2v[j] = bn2[gnv[j]]; }
    #pragma unroll
    for (int i = 0; i < 2; ++i) {
        #pragma unroll
        for (int r = 0; r < 4; ++r) {
            int lrow = wr * 32 + i * 16 + lk * 4 + r;
            int gm = m0 + lrow;
            float a2 = an2[gm];
            float sc = escale[gm];
            float rs = 0.f;
            #pragma unroll
            for (int j = 0; j < 2; ++j) {
                float dv = fmaxf(a2 + bn2v[j] - 2.0f * acc[i][j][r], 0.0f);
                float ev = __expf(dv * sc);
                if (MODE == 1) {
                    short hb = f2bf(ev);
                    Eout[(size_t)gm * NS + gnv[j]] = hb;
                    rs += bf2f(hb);
                } else {
                    esum[lrow][wc * 32 + j * 16 + lr] = ev;
                }
            }
            if (MODE == 1) {
                #pragma unroll
                for (int m = 1; m < 16; m <<= 1) rs += __shfl_xor(rs, m);
                if (lr == 0) se[wc][lrow] = rs;
            }
        }
    }
    if (MODE == 1) {
        __syncthreads();
        if (t < 64)
            sumEp[(size_t)(m0 + t) * 64 + blockIdx.y] = se[0][t] + se[1][t];
    } else {
        __syncthreads();
        {
            int row = t >> 2, q = t & 3;
            float accs[NCLS] = {};
            #pragma unroll
            for (int c = 0; c < 16; ++c) {
                int col = q * 16 + c;
                float ev = esum[row][col];
                int lb = lbl_l[col];
                #pragma unroll
                for (int cc = 0; cc < NCLS; ++cc) accs[cc] += (lb == cc) ? ev : 0.f;
            }
            #pragma unroll
            for (int cc = 0; cc < NCLS; ++cc) ybq[row][q][cc] = accs[cc];
        }
        __syncthreads();
        if (t < 64) {
            float o[NCLS];
            #pragma unroll
            for (int cc = 0; cc < NCLS; ++cc)
                o[cc] = ybq[t][0][cc] + ybq[t][1][cc] + ybq[t][2][cc] + ybq[t][3][cc];
            float* dst = ybin + ((size_t)blockIdx.y * BB + (m0 + t)) * NCLS;
            #pragma unroll
            for (int q2 = 0; q2 < NCLS; q2 += 2) {
                float2 v; v.x = o[q2]; v.y = o[q2 + 1];
                *(float2*)(dst + q2) = v;
            }
        }
    }
}

// ====== MFMA GEMM raw partials, 8 waves / 512 thr (w = e @ fromT, K-split 8) ======
__global__ __launch_bounds__(512)
void gemm_bt8(const short* __restrict__ A, const short* __restrict__ B, int K,
              int kslab, int nt, float* __restrict__ C, int ldc, size_t cstride)
{
    __shared__ short As[2][64][LDSP];
    __shared__ short Bs[2][128][LDSP];
    int t = threadIdx.x;
    int m0 = blockIdx.x * 64;
    int n0 = blockIdx.y * 128;
    int kbase = blockIdx.z * kslab;
    float* Cp = C + (size_t)blockIdx.z * cstride;
    int wid = t >> 6, lane = t & 63;
    int wr = wid >> 2, wc = wid & 3;      // 2 x 4 waves
    int lr = lane & 15, lk = lane >> 4;

    int ar = t >> 3, ak = (t & 7) * 8;
    int br = t >> 2, bk = (t & 3) * 16;
    const short* Ag = A + (size_t)(m0 + ar) * K + kbase + ak;
    const short* Bg = B + (size_t)(n0 + br) * K + kbase + bk;

    f32x4 acc[2][2] = {};
    bf16x8 ra0 = *(const bf16x8*)Ag;
    bf16x8 rb0 = *(const bf16x8*)Bg;
    bf16x8 rb1 = *(const bf16x8*)(Bg + 8);
    int cur = 0;
    *(bf16x8*)&As[0][ar][ak]     = ra0;
    *(bf16x8*)&Bs[0][br][bk]     = rb0;
    *(bf16x8*)&Bs[0][br][bk + 8] = rb1;

    for (int it = 0; it < nt; ++it) {
        __syncthreads();
        if (it + 1 < nt) {
            int ko = (it + 1) * 64;
            ra0 = *(const bf16x8*)(Ag + ko);
            rb0 = *(const bf16x8*)(Bg + ko);
            rb1 = *(const bf16x8*)(Bg + ko + 8);
        }
        #pragma unroll
        for (int ks = 0; ks < 2; ++ks) {
            int k0 = ks * 32 + lk * 8;
            bf16x8 af[2], bfr[2];
            #pragma unroll
            for (int i = 0; i < 2; ++i)
                af[i] = *(const bf16x8*)&As[cur][wr * 32 + i * 16 + lr][k0];
            #pragma unroll
            for (int j = 0; j < 2; ++j)
                bfr[j] = *(const bf16x8*)&Bs[cur][wc * 32 + j * 16 + lr][k0];
            #pragma unroll
            for (int i = 0; i < 2; ++i)
                #pragma unroll
                for (int j = 0; j < 2; ++j)
                    acc[i][j] = __builtin_amdgcn_mfma_f32_16x16x32_bf16(
                        af[i], bfr[j], acc[i][j], 0, 0, 0);
        }
        if (it + 1 < nt) {
            cur ^= 1;
            *(bf16x8*)&As[cur][ar][ak]     = ra0;
            *(bf16x8*)&Bs[cur][br][bk]     = rb0;
            *(bf16x8*)&Bs[cur][br][bk + 8] = rb1;
        }
    }
    #pragma unroll
    for (int i = 0; i < 2; ++i) {
        #pragma unroll
        for (int r = 0; r < 4; ++r) {
            int gm = m0 + wr * 32 + i * 16 + lk * 4 + r;
            #pragma unroll
            for (int j = 0; j < 2; ++j) {
                int gn = n0 + wc * 32 + j * 16 + lr;
                Cp[(size_t)gm * ldc + gn] = acc[i][j][r];
            }
        }
    }
}

// === xt = (sum of 8 w-slabs)/sumE (or matched row) -> bf16 + norm + escale2 ===
__global__ __launch_bounds__(256)
void xt_fin(const float* __restrict__ wpart, const float* __restrict__ sumEp,
            const int* __restrict__ midx, const float* __restrict__ fromf,
            const float* __restrict__ fbar, const float* __restrict__ fms,
            short* __restrict__ xtb, float* __restrict__ xtn2,
            float* __restrict__ escale2)
{
    __shared__ float red[4];
    int b = blockIdx.x;
    int t = threadIdx.x;
    int d = t * 2;
    int mi = midx[b];
    float sv = (t < 64) ? sumEp[(size_t)b * 64 + t] : 0.f;
    float stot = block_sum(sv, red);
    float inv = 1.0f / stot;
    float v0 = 0.f, v1 = 0.f;
    #pragma unroll
    for (int sl = 0; sl < 8; ++sl) {
        float2 p = *(const float2*)(wpart + (size_t)sl * (BB * DDIM) + (size_t)b * DDIM + d);
        v0 += p.x; v1 += p.y;
    }
    v0 *= inv; v1 *= inv;
    if (mi < NS) {
        v0 = fromf[(size_t)mi * DDIM + d];
        v1 = fromf[(size_t)mi * DDIM + d + 1];
    }
    xtb[(size_t)b * DDIM + d]     = f2bf(v0);
    xtb[(size_t)b * DDIM + d + 1] = f2bf(v1);
    float nt2 = block_sum(v0 * v0 + v1 * v1, red);
    float2 fb2 = *(const float2*)(fbar + d);
    float fd = block_sum(v0 * fb2.x + v1 * fb2.y, red);
    if (t == 0) {
        xtn2[b] = nt2;
        escale2[b] = -TEMP / (fms[0] + nt2 - 2.0f * fd);
    }
}

// =============== ystar_red: 512 blocks, reduce ybin[64 nt][b][NCLS] -> out ===============
__global__ __launch_bounds__(256)
void ystar_red(const float* __restrict__ ybin, float* __restrict__ out)
{
    __shared__ float p[64][NCLS + 2];
    __shared__ float nums[NCLS];
    int b = blockIdx.x, t = threadIdx.x;
    if (t < 64) {
        const float* src = ybin + ((size_t)t * BB + b) * NCLS;
        #pragma unroll
        for (int q = 0; q < NCLS; q += 2) {
            float2 v = *(const float2*)(src + q);
            p[t][q] = v.x; p[t][q + 1] = v.y;
        }
    }
    __syncthreads();
    if (t < NCLS) {
        float s = 0.f;
        #pragma unroll 8
        for (int k = 0; k < 64; ++k) s += p[k][t];
        nums[t] = s;
    }
    __syncthreads();
    if (t < NCLS) {
        float den = 0.f;
        #pragma unroll
        for (int c = 0; c < NCLS; ++c) den += nums[c];
        out[b * NCLS + t] = nums[t] / den;
    }
}

extern "C" void kernel_launch(void* const* d_in, const int* in_sizes, int n_in,
                              void* d_out, int out_size, void* d_ws, size_t ws_size,
                              hipStream_t stream) {
    const float* x     = (const float*)d_in[0];
    const float* star  = (const float*)d_in[1];
    const float* from  = (const float*)d_in[2];
    const int*   label = (const int*)d_in[3];
    float* out = (float*)d_out;

    float* F = (float*)d_ws;                     // ~33 MB of workspace
    float* wpart = F;                            // 8 x [512][512] f32 (8 MB)
    short* Sb    = (short*)(F + 2097152);        // star bf16  [4096][512] (4 MB)
    short* FTb   = (short*)(F + 3145728);        // fromT bf16 [512][4096] (4 MB)
    short* Fb    = (short*)(F + 4194304);        // from bf16  [4096][512] (4 MB)
    short* Eb    = (short*)(F + 5242880);        // eT bf16    [512][4096] (4 MB)
    float* ybin  = F + 6291456;                  // [64][512][10] f32 (1.25 MB)
    short* Xb    = (short*)(F + 7340032);        // x bf16     [512][512]
    short* XTb   = (short*)(F + 7471104);        // xt bf16    [512][512]
    float* sn2   = F + 7602176;                  // 4096
    float* fn2   = F + 7606272;                  // 4096
    float* xn2   = F + 7610368;                  // 512
    float* xtn2  = F + 7610880;                  // 512
    float* esc1  = F + 7611392;                  // 512
    float* esc2  = F + 7611904;                  // 512
    float* sbar  = F + 7612416;                  // 512
    float* fbar  = F + 7612928;                  // 512
    float* sms   = F + 7613440;                  // 16
    float* fms   = F + 7613456;                  // 16
    float* sumEp = F + 7613472;                  // [512][64]
    float* scol  = F + 7646240;                  // 4096
    float* xcol  = F + 7650336;                  // 512
    int*   midx  = (int*)(F + 7650848);          // 512
    float* spart = F + 7651360;                  // [1024][512] (2 MB)
    float* fpart2= F + 8175648;                  // [64][512]
    float* rowpart = F + 8208416;                // [8][4096]

    prep<<<1664, 256, 0, stream>>>(x, star, from, Xb, Sb, FTb, Fb,
                                   xn2, sn2, scol, xcol, midx,
                                   spart, fpart2, rowpart);
    finmatch<<<66, 256, 0, stream>>>(spart, fpart2, rowpart, sn2, fn2,
                                     sbar, fbar, sms, fms,
                                     x, star, scol, xcol, midx);
    esc1k<<<128, 256, 0, stream>>>(x, sbar, sms, xn2, esc1);
    // eT[b][n] = bf16(exp(esc1[b]*clamp(xn2+sn2-2 x.star,0))) + sumE partials
    gemm_exp<1><<<dim3(8, 64), 256, 0, stream>>>(Xb, Sb, xn2, sn2, esc1, Eb, sumEp,
                                                 nullptr, nullptr, 8);
    // wpart[z][b][d] = sum_{n in slab z} eT[b][n]*fromT[d][n]  (8 slabs of K=512)
    gemm_bt8<<<dim3(8, 4, 8), 512, 0, stream>>>(Eb, FTb, NS, 512, 8, wpart, DDIM,
                                                (size_t)BB * DDIM);
    xt_fin<<<BB, 256, 0, stream>>>(wpart, sumEp, midx, from, fbar, fms,
                                   XTb, xtn2, esc2);
    // e2 = exp(esc2[b]*clamp(xtn2+fn2-2 xt.from,0)) binned by label -> ybin partials
    gemm_exp<2><<<dim3(8, 64), 256, 0, stream>>>(XTb, Fb, xtn2, fn2, esc2, nullptr,
                                                 nullptr, label, ybin, 8);
    ystar_red<<<BB, 256, 0, stream>>>(ybin, out);
}

// Round 19
// 67.677 us; speedup vs baseline: 1.0080x; 1.0080x over previous
//
#include <hip/hip_runtime.h>

#define TEMP 10.0f
#define NS 4096
#define BB 512
#define DDIM 512
#define NCLS 10
#define LDSP 72

typedef short bf16x8 __attribute__((ext_vector_type(8)));
typedef float f32x4 __attribute__((ext_vector_type(4)));

__device__ inline short f2bf(float f) {
    unsigned u = __builtin_bit_cast(unsigned, f);
    u += 0x7FFFu + ((u >> 16) & 1u);      // round-to-nearest-even
    return (short)(u >> 16);
}
__device__ inline float bf2f(short h) {
    unsigned u = ((unsigned)(unsigned short)h) << 16;
    return __builtin_bit_cast(float, u);
}

// =============== block-wide sum helper (256 threads) ===============
__device__ inline float block_sum(float s, float* red) {
    #pragma unroll
    for (int off = 32; off > 0; off >>= 1) s += __shfl_down(s, off);
    int wid = threadIdx.x >> 6;
    if ((threadIdx.x & 63) == 0) red[wid] = s;
    __syncthreads();
    float tot = red[0] + red[1] + red[2] + red[3];
    __syncthreads();
    return tot;
}

// =============== prep: conversions / norms / col0 / in-block colsum partials ===========
__global__ __launch_bounds__(256)
void prep(const float* __restrict__ x, const float* __restrict__ star,
          const float* __restrict__ from,
          short* __restrict__ Xb, short* __restrict__ Sb,
          short* __restrict__ FTb, short* __restrict__ Fb,
          float* __restrict__ xn2, float* __restrict__ sn2, float* __restrict__ fn2,
          float* __restrict__ scol, float* __restrict__ xcol, int* __restrict__ midx,
          float* __restrict__ spart, float* __restrict__ fpart)
{
    __shared__ short tile[64][LDSP];      // conv path aliases as float cp[2048]
    int bid = blockIdx.x, t = threadIdx.x;
    if (bid < 2176) {
        const float* in; short* outb; float* n2; float* colb; float* part; int rowbase;
        if (bid < 1024)      { in = star; outb = Sb; n2 = sn2; colb = scol; rowbase = bid * 4;
                               part = spart + (size_t)bid * 512; }
        else if (bid < 1152) { in = x;    outb = Xb; n2 = xn2; colb = xcol; rowbase = (bid - 1024) * 4;
                               part = nullptr; }
        else                 { in = from; outb = Fb; n2 = fn2; colb = nullptr; rowbase = (bid - 1152) * 4;
                               part = fpart + (size_t)(bid - 1152) * 512; }
        if (bid == 1024) { midx[t] = NS; midx[256 + t] = NS; }
        int w = t >> 6;
        int row = rowbase + w;
        int l = t & 63;
        const float4* p = (const float4*)(in + (size_t)row * DDIM) + l * 2;
        float4 a = p[0], b = p[1];
        float s = a.x*a.x + a.y*a.y + a.z*a.z + a.w*a.w
                + b.x*b.x + b.y*b.y + b.z*b.z + b.w*b.w;
        bf16x8 h;
        h[0]=f2bf(a.x); h[1]=f2bf(a.y); h[2]=f2bf(a.z); h[3]=f2bf(a.w);
        h[4]=f2bf(b.x); h[5]=f2bf(b.y); h[6]=f2bf(b.z); h[7]=f2bf(b.w);
        *(bf16x8*)(outb + (size_t)row * DDIM + l * 8) = h;
        #pragma unroll
        for (int off = 32; off > 0; off >>= 1) s += __shfl_down(s, off);
        if (l == 0) {
            n2[row] = s;
            if (colb) colb[row] = a.x;
        }
        if (part) {
            float* cp = (float*)tile;    // [4][512]
            *(float4*)&cp[w * 512 + l * 8]     = a;
            *(float4*)&cp[w * 512 + l * 8 + 4] = b;
            __syncthreads();
            int c = t * 2;
            float2 o;
            o.x = cp[c]     + cp[512 + c]     + cp[1024 + c]     + cp[1536 + c];
            o.y = cp[c + 1] + cp[512 + c + 1] + cp[1024 + c + 1] + cp[1536 + c + 1];
            *(float2*)&part[c] = o;
        }
        return;
    }
    // ---- from transpose tile ----
    int tid2 = bid - 2176;
    int n0 = (tid2 & 63) * 64, d0 = (tid2 >> 6) * 64;
    int r = t >> 4, c4 = (t & 15) * 4;
    #pragma unroll
    for (int rr = 0; rr < 64; rr += 16) {
        float4 v = *(const float4*)(from + (size_t)(n0 + r + rr) * DDIM + d0 + c4);
        tile[r + rr][c4 + 0] = f2bf(v.x);
        tile[r + rr][c4 + 1] = f2bf(v.y);
        tile[r + rr][c4 + 2] = f2bf(v.z);
        tile[r + rr][c4 + 3] = f2bf(v.w);
    }
    __syncthreads();
    int dr = t >> 2, nco = (t & 3) * 16;
    short tmp[16];
    #pragma unroll
    for (int q = 0; q < 16; ++q) tmp[q] = tile[nco + q][dr];
    short* op = FTb + (size_t)(d0 + dr) * NS + n0 + nco;
    *(bf16x8*)op       = *(bf16x8*)tmp;
    *(bf16x8*)(op + 8) = *(bf16x8*)(tmp + 8);
}

// ===== finmatch: 50 blocks =====
__global__ __launch_bounds__(256)
void finmatch(const float* __restrict__ spart, const float* __restrict__ fpart,
              const float* __restrict__ sn2, const float* __restrict__ fn2,
              float* __restrict__ sbar, float* __restrict__ fbar,
              float* __restrict__ sms, float* __restrict__ fms,
              const float* __restrict__ x, const float* __restrict__ star,
              const float* __restrict__ scol, const float* __restrict__ xcol,
              int* __restrict__ midx)
{
    int bid = blockIdx.x, t = threadIdx.x;
    if (bid < 32) {
        __shared__ float red2[8][33];
        int m = bid & 1;
        int c0 = (bid >> 1) * 32;
        const float* part = m ? fpart : spart;
        float* outm = m ? fbar : sbar;
        int c = c0 + (t & 31);
        int p0 = (t >> 5) * 128;             // 8 groups x 128 partials
        float s = 0.f;
        #pragma unroll 8
        for (int p = 0; p < 128; ++p)
            s += part[(size_t)(p0 + p) * 512 + c];
        red2[t >> 5][t & 31] = s;
        __syncthreads();
        if (t < 32) {
            float tot = 0.f;
            #pragma unroll
            for (int q = 0; q < 8; ++q) tot += red2[q][t];
            outm[c0 + t] = tot * (1.0f / NS);
        }
        return;
    }
    if (bid < 34) {
        __shared__ float red[4];
        int m = bid - 32;
        const float* n2v = m ? fn2 : sn2;
        float* outs = m ? fms : sms;
        float s = 0.f;
        #pragma unroll
        for (int q = 0; q < 16; ++q) s += n2v[q * 256 + t];
        float tot = block_sum(s, red);
        if (t == 0) outs[0] = tot * (1.0f / NS);
        return;
    }
    // ---- exact-match scan ----
    __shared__ float xl[BB];
    *(float2*)&xl[t * 2] = *(const float2*)&xcol[t * 2];
    __syncthreads();
    int n = (bid - 34) * 256 + t;
    float sv = scol[n];
    #pragma unroll 4
    for (int b4 = 0; b4 < BB; b4 += 4) {
        float4 xv = *(const float4*)&xl[b4];
        if (xv.x == sv || xv.y == sv || xv.z == sv || xv.w == sv) {
            #pragma unroll
            for (int j = 0; j < 4; ++j) {
                int b = b4 + j;
                if (xl[b] == sv) {
                    const float* xr = x + (size_t)b * DDIM;
                    const float* sr = star + (size_t)n * DDIM;
                    bool eq = true;
                    for (int k = 0; k < DDIM && eq; k += 4) {
                        float4 a = *(const float4*)(xr + k);
                        float4 c4v = *(const float4*)(sr + k);
                        eq = (a.x == c4v.x) && (a.y == c4v.y) &&
                             (a.z == c4v.z) && (a.w == c4v.w);
                    }
                    if (eq) atomicMin(&midx[b], n);
                }
            }
        }
    }
}

// ===== esc1k: 128 blocks, escale1[b] = -T / (sms + xn2[b] - 2*sbar.x_b) =====
__global__ __launch_bounds__(256)
void esc1k(const float* __restrict__ x, const float* __restrict__ sbar,
           const float* __restrict__ sms, const float* __restrict__ xn2,
           float* __restrict__ escale1)
{
    int t = threadIdx.x;
    int lane = t & 63, w = t >> 6;
    int b = blockIdx.x * 4 + w;
    const float4* xp = (const float4*)(x + (size_t)b * DDIM) + lane * 2;
    const float4* sp = (const float4*)sbar + lane * 2;
    float4 xa = xp[0], xb = xp[1], sa = sp[0], sb = sp[1];
    float dot = xa.x*sa.x + xa.y*sa.y + xa.z*sa.z + xa.w*sa.w
              + xb.x*sb.x + xb.y*sb.y + xb.z*sb.z + xb.w*sb.w;
    #pragma unroll
    for (int m = 32; m > 0; m >>= 1) dot += __shfl_xor(dot, m);
    if (lane == 0)
        escale1[b] = -TEMP / (sms[0] + xn2[b] - 2.0f * dot);
}

// ====== MFMA GEMM + fused sqdist/exp epilogue ======
// BM=BN=64, 256 thr / 4 waves (2x2), acc[2][2], double-buffered, grid (8,64)=512 blocks.
// MODE 1: Eout bf16 write + sumEp[m][64] per-n-tile partial sums (first distance GEMM).
// MODE 2: no Eout; per-row class bins -> ybin[nt][b][NCLS] (second distance GEMM + ystar).
template<int MODE>
__global__ __launch_bounds__(256)
void gemm_exp(const short* __restrict__ A, const short* __restrict__ B,
              const float* __restrict__ an2, const float* __restrict__ bn2,
              const float* __restrict__ escale, short* __restrict__ Eout,
              float* __restrict__ sumEp, const int* __restrict__ labels,
              float* __restrict__ ybin, int nt)
{
    __shared__ short As[2][64][LDSP];
    __shared__ short Bs[2][64][LDSP];
    __shared__ float se[2][64];
    __shared__ float esum[64][65];
    __shared__ float ybq[64][4][NCLS];
    __shared__ int lbl_l[64];
    const int K = DDIM;
    int t = threadIdx.x;
    int m0 = blockIdx.x * 64;
    int n0 = blockIdx.y * 64;
    int wid = t >> 6, lane = t & 63;
    int wr = wid >> 1, wc = wid & 1;
    int lr = lane & 15, lk = lane >> 4;

    int ar = t >> 2, ak = (t & 3) * 16;
    const short* Ag = A + (size_t)(m0 + ar) * K + ak;
    const short* Bg = B + (size_t)(n0 + ar) * K + ak;

    f32x4 acc[2][2] = {};
    bf16x8 ra0 = *(const bf16x8*)Ag;
    bf16x8 ra1 = *(const bf16x8*)(Ag + 8);
    bf16x8 rb0 = *(const bf16x8*)Bg;
    bf16x8 rb1 = *(const bf16x8*)(Bg + 8);
    int cur = 0;
    *(bf16x8*)&As[0][ar][ak]     = ra0;
    *(bf16x8*)&As[0][ar][ak + 8] = ra1;
    *(bf16x8*)&Bs[0][ar][ak]     = rb0;
    *(bf16x8*)&Bs[0][ar][ak + 8] = rb1;
    if (MODE == 2 && t < 64) lbl_l[t] = labels[n0 + t];

    for (int it = 0; it < nt; ++it) {
        __syncthreads();
        if (it + 1 < nt) {
            int ko = (it + 1) * 64;
            ra0 = *(const bf16x8*)(Ag + ko);
            ra1 = *(const bf16x8*)(Ag + ko + 8);
            rb0 = *(const bf16x8*)(Bg + ko);
            rb1 = *(const bf16x8*)(Bg + ko + 8);
        }
        #pragma unroll
        for (int ks = 0; ks < 2; ++ks) {
            int k0 = ks * 32 + lk * 8;
            bf16x8 af[2], bfr[2];
            #pragma unroll
            for (int i = 0; i < 2; ++i)
                af[i] = *(const bf16x8*)&As[cur][wr * 32 + i * 16 + lr][k0];
            #pragma unroll
            for (int j = 0; j < 2; ++j)
                bfr[j] = *(const bf16x8*)&Bs[cur][wc * 32 + j * 16 + lr][k0];
            #pragma unroll
            for (int i = 0; i < 2; ++i)
                #pragma unroll
                for (int j = 0; j < 2; ++j)
                    acc[i][j] = __builtin_amdgcn_mfma_f32_16x16x32_bf16(
                        af[i], bfr[j], acc[i][j], 0, 0, 0);
        }
        if (it + 1 < nt) {
            cur ^= 1;
            *(bf16x8*)&As[cur][ar][ak]     = ra0;
            *(bf16x8*)&As[cur][ar][ak + 8] = ra1;
            *(bf16x8*)&Bs[cur][ar][ak]     = rb0;
            *(bf16x8*)&Bs[cur][ar][ak + 8] = rb1;
        }
    }
    // ---- epilogue ----
    float bn2v[2];
    int gnv[2];
    #pragma unroll
    for (int j = 0; j < 2; ++j) { gnv[j] = n0 + wc * 32 + j * 16 + lr; bn2v[j] = bn2[gnv[j]]; }
    #pragma unroll
    for (int i = 0; i < 2; ++i) {
        #pragma unroll
        for (int r = 0; r < 4; ++r) {
            int lrow = wr * 32 + i * 16 + lk * 4 + r;
            int gm = m0 + lrow;
            float a2 = an2[gm];
            float sc = escale[gm];
            float rs = 0.f;
            #pragma unroll
            for (int j = 0; j < 2; ++j) {
                float dv = fmaxf(a2 + bn2v[j] - 2.0f * acc[i][j][r], 0.0f);
                float ev = __expf(dv * sc);
                if (MODE == 1) {
                    short hb = f2bf(ev);
                    Eout[(size_t)gm * NS + gnv[j]] = hb;
                    rs += bf2f(hb);
                } else {
                    esum[lrow][wc * 32 + j * 16 + lr] = ev;
                }
            }
            if (MODE == 1) {
                #pragma unroll
                for (int m = 1; m < 16; m <<= 1) rs += __shfl_xor(rs, m);
                if (lr == 0) se[wc][lrow] = rs;
            }
        }
    }
    if (MODE == 1) {
        __syncthreads();
        if (t < 64)
            sumEp[(size_t)(m0 + t) * 64 + blockIdx.y] = se[0][t] + se[1][t];
    } else {
        __syncthreads();
        // binning: thread t handles (row=t>>2, col quarter q=t&3)
        {
            int row = t >> 2, q = t & 3;
            float accs[NCLS] = {};
            #pragma unroll
            for (int c = 0; c < 16; ++c) {
                int col = q * 16 + c;
                float ev = esum[row][col];
                int lb = lbl_l[col];
                #pragma unroll
                for (int cc = 0; cc < NCLS; ++cc) accs[cc] += (lb == cc) ? ev : 0.f;
            }
            #pragma unroll
            for (int cc = 0; cc < NCLS; ++cc) ybq[row][q][cc] = accs[cc];
        }
        __syncthreads();
        if (t < 64) {
            float o[NCLS];
            #pragma unroll
            for (int cc = 0; cc < NCLS; ++cc)
                o[cc] = ybq[t][0][cc] + ybq[t][1][cc] + ybq[t][2][cc] + ybq[t][3][cc];
            float* dst = ybin + ((size_t)blockIdx.y * BB + (m0 + t)) * NCLS;
            #pragma unroll
            for (int q2 = 0; q2 < NCLS; q2 += 2) {
                float2 v; v.x = o[q2]; v.y = o[q2 + 1];
                *(float2*)(dst + q2) = v;
            }
        }
    }
}

// ====== MFMA GEMM raw partials, 8 waves / 512 thr (w = e @ fromT, K-split 8) ======
__global__ __launch_bounds__(512)
void gemm_bt8(const short* __restrict__ A, const short* __restrict__ B, int K,
              int kslab, int nt, float* __restrict__ C, int ldc, size_t cstride)
{
    __shared__ short As[2][64][LDSP];
    __shared__ short Bs[2][128][LDSP];
    int t = threadIdx.x;
    int m0 = blockIdx.x * 64;
    int n0 = blockIdx.y * 128;
    int kbase = blockIdx.z * kslab;
    float* Cp = C + (size_t)blockIdx.z * cstride;
    int wid = t >> 6, lane = t & 63;
    int wr = wid >> 2, wc = wid & 3;      // 2 x 4 waves
    int lr = lane & 15, lk = lane >> 4;

    int ar = t >> 3, ak = (t & 7) * 8;
    int br = t >> 2, bk = (t & 3) * 16;
    const short* Ag = A + (size_t)(m0 + ar) * K + kbase + ak;
    const short* Bg = B + (size_t)(n0 + br) * K + kbase + bk;

    f32x4 acc[2][2] = {};
    bf16x8 ra0 = *(const bf16x8*)Ag;
    bf16x8 rb0 = *(const bf16x8*)Bg;
    bf16x8 rb1 = *(const bf16x8*)(Bg + 8);
    int cur = 0;
    *(bf16x8*)&As[0][ar][ak]     = ra0;
    *(bf16x8*)&Bs[0][br][bk]     = rb0;
    *(bf16x8*)&Bs[0][br][bk + 8] = rb1;

    for (int it = 0; it < nt; ++it) {
        __syncthreads();
        if (it + 1 < nt) {
            int ko = (it + 1) * 64;
            ra0 = *(const bf16x8*)(Ag + ko);
            rb0 = *(const bf16x8*)(Bg + ko);
            rb1 = *(const bf16x8*)(Bg + ko + 8);
        }
        #pragma unroll
        for (int ks = 0; ks < 2; ++ks) {
            int k0 = ks * 32 + lk * 8;
            bf16x8 af[2], bfr[2];
            #pragma unroll
            for (int i = 0; i < 2; ++i)
                af[i] = *(const bf16x8*)&As[cur][wr * 32 + i * 16 + lr][k0];
            #pragma unroll
            for (int j = 0; j < 2; ++j)
                bfr[j] = *(const bf16x8*)&Bs[cur][wc * 32 + j * 16 + lr][k0];
            #pragma unroll
            for (int i = 0; i < 2; ++i)
                #pragma unroll
                for (int j = 0; j < 2; ++j)
                    acc[i][j] = __builtin_amdgcn_mfma_f32_16x16x32_bf16(
                        af[i], bfr[j], acc[i][j], 0, 0, 0);
        }
        if (it + 1 < nt) {
            cur ^= 1;
            *(bf16x8*)&As[cur][ar][ak]     = ra0;
            *(bf16x8*)&Bs[cur][br][bk]     = rb0;
            *(bf16x8*)&Bs[cur][br][bk + 8] = rb1;
        }
    }
    #pragma unroll
    for (int i = 0; i < 2; ++i) {
        #pragma unroll
        for (int r = 0; r < 4; ++r) {
            int gm = m0 + wr * 32 + i * 16 + lk * 4 + r;
            #pragma unroll
            for (int j = 0; j < 2; ++j) {
                int gn = n0 + wc * 32 + j * 16 + lr;
                Cp[(size_t)gm * ldc + gn] = acc[i][j][r];
            }
        }
    }
}

// === xt = (sum of 8 w-slabs)/sumE (or matched row) -> bf16 + norm + escale2 ===
__global__ __launch_bounds__(256)
void xt_fin(const float* __restrict__ wpart, const float* __restrict__ sumEp,
            const int* __restrict__ midx, const float* __restrict__ fromf,
            const float* __restrict__ fbar, const float* __restrict__ fms,
            short* __restrict__ xtb, float* __restrict__ xtn2,
            float* __restrict__ escale2)
{
    __shared__ float red[4];
    int b = blockIdx.x;
    int t = threadIdx.x;
    int d = t * 2;
    int mi = midx[b];
    float sv = (t < 64) ? sumEp[(size_t)b * 64 + t] : 0.f;
    float stot = block_sum(sv, red);
    float inv = 1.0f / stot;
    float v0 = 0.f, v1 = 0.f;
    #pragma unroll
    for (int sl = 0; sl < 8; ++sl) {
        float2 p = *(const float2*)(wpart + (size_t)sl * (BB * DDIM) + (size_t)b * DDIM + d);
        v0 += p.x; v1 += p.y;
    }
    v0 *= inv; v1 *= inv;
    if (mi < NS) {
        v0 = fromf[(size_t)mi * DDIM + d];
        v1 = fromf[(size_t)mi * DDIM + d + 1];
    }
    xtb[(size_t)b * DDIM + d]     = f2bf(v0);
    xtb[(size_t)b * DDIM + d + 1] = f2bf(v1);
    float nt2 = block_sum(v0 * v0 + v1 * v1, red);
    float2 fb2 = *(const float2*)(fbar + d);
    float fd = block_sum(v0 * fb2.x + v1 * fb2.y, red);
    if (t == 0) {
        xtn2[b] = nt2;
        escale2[b] = -TEMP / (fms[0] + nt2 - 2.0f * fd);
    }
}

// =============== ystar_red: 512 blocks, reduce ybin[64 nt][b][NCLS] -> out ===============
__global__ __launch_bounds__(256)
void ystar_red(const float* __restrict__ ybin, float* __restrict__ out)
{
    __shared__ float p[64][NCLS + 2];
    __shared__ float nums[NCLS];
    int b = blockIdx.x, t = threadIdx.x;
    if (t < 64) {
        const float* src = ybin + ((size_t)t * BB + b) * NCLS;
        #pragma unroll
        for (int q = 0; q < NCLS; q += 2) {
            float2 v = *(const float2*)(src + q);
            p[t][q] = v.x; p[t][q + 1] = v.y;
        }
    }
    __syncthreads();
    if (t < NCLS) {
        float s = 0.f;
        #pragma unroll 8
        for (int k = 0; k < 64; ++k) s += p[k][t];
        nums[t] = s;
    }
    __syncthreads();
    if (t < NCLS) {
        float den = 0.f;
        #pragma unroll
        for (int c = 0; c < NCLS; ++c) den += nums[c];
        out[b * NCLS + t] = nums[t] / den;
    }
}

extern "C" void kernel_launch(void* const* d_in, const int* in_sizes, int n_in,
                              void* d_out, int out_size, void* d_ws, size_t ws_size,
                              hipStream_t stream) {
    const float* x     = (const float*)d_in[0];
    const float* star  = (const float*)d_in[1];
    const float* from  = (const float*)d_in[2];
    const int*   label = (const int*)d_in[3];
    float* out = (float*)d_out;

    float* F = (float*)d_ws;                     // ~33 MB of workspace
    float* wpart = F;                            // 8 x [512][512] f32 (8 MB)
    short* Sb    = (short*)(F + 2097152);        // star bf16  [4096][512] (4 MB)
    short* FTb   = (short*)(F + 3145728);        // fromT bf16 [512][4096] (4 MB)
    short* Fb    = (short*)(F + 4194304);        // from bf16  [4096][512] (4 MB)
    short* Eb    = (short*)(F + 5242880);        // eT bf16    [512][4096] (4 MB)
    float* ybin  = F + 6291456;                  // [64][512][10] f32 (1.25 MB)
    short* Xb    = (short*)(F + 7340032);        // x bf16     [512][512]
    short* XTb   = (short*)(F + 7471104);        // xt bf16    [512][512]
    float* sn2   = F + 7602176;                  // 4096
    float* fn2   = F + 7606272;                  // 4096
    float* xn2   = F + 7610368;                  // 512
    float* xtn2  = F + 7610880;                  // 512
    float* esc1  = F + 7611392;                  // 512
    float* esc2  = F + 7611904;                  // 512
    float* sbar  = F + 7612416;                  // 512
    float* fbar  = F + 7612928;                  // 512
    float* sms   = F + 7613440;                  // 16
    float* fms   = F + 7613456;                  // 16
    float* sumEp = F + 7613472;                  // [512][64]
    float* scol  = F + 7646240;                  // 4096
    float* xcol  = F + 7650336;                  // 512
    int*   midx  = (int*)(F + 7650848);          // 512
    float* spart = F + 7651360;                  // [1024][512] (2 MB)
    float* fpart = F + 8175648;                  // [1024][512] (2 MB)

    prep<<<2688, 256, 0, stream>>>(x, star, from, Xb, Sb, FTb, Fb,
                                   xn2, sn2, fn2, scol, xcol, midx, spart, fpart);
    finmatch<<<50, 256, 0, stream>>>(spart, fpart, sn2, fn2, sbar, fbar, sms, fms,
                                     x, star, scol, xcol, midx);
    esc1k<<<128, 256, 0, stream>>>(x, sbar, sms, xn2, esc1);
    // eT[b][n] = bf16(exp(esc1[b]*clamp(xn2+sn2-2 x.star,0))) + sumE partials
    gemm_exp<1><<<dim3(8, 64), 256, 0, stream>>>(Xb, Sb, xn2, sn2, esc1, Eb, sumEp,
                                                 nullptr, nullptr, 8);
    // wpart[z][b][d] = sum_{n in slab z} eT[b][n]*fromT[d][n]  (8 slabs of K=512)
    gemm_bt8<<<dim3(8, 4, 8), 512, 0, stream>>>(Eb, FTb, NS, 512, 8, wpart, DDIM,
                                                (size_t)BB * DDIM);
    xt_fin<<<BB, 256, 0, stream>>>(wpart, sumEp, midx, from, fbar, fms,
                                   XTb, xtn2, esc2);
    // e2 = exp(esc2[b]*clamp(xtn2+fn2-2 xt.from,0)) binned by label -> ybin partials
    gemm_exp<2><<<dim3(8, 64), 256, 0, stream>>>(XTb, Fb, xtn2, fn2, esc2, nullptr,
                                                 nullptr, label, ybin, 8);
    ystar_red<<<BB, 256, 0, stream>>>(ybin, out);
}